// Round 10
// baseline (2563.346 us; speedup 1.0000x reference)
//
#include <hip/hip_runtime.h>
#include <cstdint>

typedef __attribute__((ext_vector_type(4))) float f32x4;
typedef __attribute__((ext_vector_type(8))) short s16x8;
typedef __attribute__((ext_vector_type(4))) short s16x4;
typedef unsigned short u16;
typedef unsigned int u32;
typedef __attribute__((address_space(1))) void gas_void;
typedef __attribute__((address_space(3))) void las_void;

#define B_ 4
#define T_ 1024
#define V_ 32000
#define D_ 1024
#define H_ 16
#define HS_ 64
#define FF_ 4096
#define L_ 8
#define BT_ (B_ * T_)

__device__ __forceinline__ float bf2f(u16 h) { return __uint_as_float(((u32)h) << 16); }
__device__ __forceinline__ u16 f2bf(float f) {
  u32 u = __float_as_uint(f);
  u += 0x7fffu + ((u >> 16) & 1u);
  return (u16)(u >> 16);
}

// async global->LDS, 16B per lane; lds dest must be wave-uniform base (+lane*16 by HW)
__device__ __forceinline__ void gld16(const void* g, void* l) {
  __builtin_amdgcn_global_load_lds((gas_void*)(uintptr_t)g,
                                   (las_void*)(u32)(uintptr_t)l, 16, 0, 0);
}

// LDS 64B-row tiles: physical chunk c holds logical k-chunk l = (c - (row>>1))&3.
// Read side: c = (l + (row>>1))&3 -> per-16-lane group every (parity,chunk)
// cell is hit exactly 2x = conflict-free (2-way is free, m136).

// ---------------------------------------------------------------------------
// GEMM 128x128 (m97 structure): QKV / FF1 / LM head. 32KB LDS -> 3-4 blk/CU.
// EPI: 0 = bf16 out; 1 = f32 + bias + residual; 2 = bf16 + bias + relu;
//      3 = f32 + bias.
// ---------------------------------------------------------------------------
template <int EPI>
__global__ __launch_bounds__(256) void gemm_bt(
    const u16* __restrict__ A, const u16* __restrict__ Bt,
    const float* __restrict__ bias, float* Cf, u16* Cb,
    int M, int N, int K) {
  __shared__ u16 lds[2][2][4096];  // [buf][A/B][128*32] = 32 KiB
  const int tid = threadIdx.x;
  const int lane = tid & 63;
  const int lr = lane & 15, hi = lane >> 4;
  const int wid = tid >> 6;
  const int wm = wid >> 1, wn = wid & 1;
  const int row0 = blockIdx.y << 7, col0 = blockIdx.x << 7;
  const int NT = K >> 5;
  const int wbase = (tid & ~63) << 4;
  const int xo = ((hi + (lr >> 1)) & 3) << 4;

  f32x4 acc[4][4];
#pragma unroll
  for (int i = 0; i < 4; ++i)
#pragma unroll
    for (int j = 0; j < 4; ++j) acc[i][j] = f32x4{0.f, 0.f, 0.f, 0.f};

  auto stage = [&](int buf, int kt) {
#pragma unroll
    for (int c = 0; c < 2; ++c) {
      const int o = (c << 12) + (tid << 4);
      const int r = o >> 6;
      const int ko = ((((o >> 4) & 3) - (r >> 1)) & 3) << 3;  // logical k elems
      gld16(A + (size_t)(row0 + r) * K + (kt << 5) + ko,
            (char*)&lds[buf][0][0] + (c << 12) + wbase);
      gld16(Bt + (size_t)(col0 + r) * K + (kt << 5) + ko,
            (char*)&lds[buf][1][0] + (c << 12) + wbase);
    }
  };

  stage(0, 0);
  __syncthreads();
  int cur = 0;
  for (int kt = 0; kt < NT; ++kt) {
    if (kt + 1 < NT) stage(cur ^ 1, kt + 1);
    const char* As = (const char*)&lds[cur][0][0];
    const char* Bs = (const char*)&lds[cur][1][0];
    s16x8 af[4], bfr[4];
#pragma unroll
    for (int i = 0; i < 4; ++i) {
      const int ra = (wm << 6) + (i << 4) + lr;
      af[i] = *(const s16x8*)(As + (ra << 6) + xo);
      const int rb = (wn << 6) + (i << 4) + lr;
      bfr[i] = *(const s16x8*)(Bs + (rb << 6) + xo);
    }
#pragma unroll
    for (int i = 0; i < 4; ++i)
#pragma unroll
      for (int j = 0; j < 4; ++j)
        acc[i][j] =
            __builtin_amdgcn_mfma_f32_16x16x32_bf16(af[i], bfr[j], acc[i][j], 0, 0, 0);
    __syncthreads();
    cur ^= 1;
  }

  const int gr = row0 + (wm << 6);
  const int gc = col0 + (wn << 6);
#pragma unroll
  for (int j = 0; j < 4; ++j) {
    const int col = gc + (j << 4) + lr;
    const float bv = (EPI != 0) ? bias[col] : 0.f;
#pragma unroll
    for (int i = 0; i < 4; ++i) {
#pragma unroll
      for (int rg = 0; rg < 4; ++rg) {
        const int row = gr + (i << 4) + (hi << 2) + rg;
        const size_t off = (size_t)row * N + col;
        float val = acc[i][j][rg] + bv;
        if constexpr (EPI == 1) val += Cf[off];
        if constexpr (EPI == 2) val = fmaxf(val, 0.f);
        if constexpr (EPI == 0 || EPI == 2) Cb[off] = f2bf(val);
        else Cf[off] = val;
      }
    }
  }
}

// ---------------------------------------------------------------------------
// gemm_bt64: 64x128 tile, BK=32, 4 waves. 24KB LDS -> 2+ blocks/CU.
// Used for proj / FF2 (small N): grid (N/128, M/64) = 512 blocks.
// EPI: 1 = f32 out + bias + residual(in-place Cf).
// ---------------------------------------------------------------------------
template <int EPI>
__global__ __launch_bounds__(256) void gemm_bt64(
    const u16* __restrict__ A, const u16* __restrict__ Bt,
    const float* __restrict__ bias, float* Cf, u16* Cb,
    int M, int N, int K) {
  __shared__ u16 lds[2][6144];  // [buf][A 2048 u16 | B 4096 u16] = 24 KiB
  const int tid = threadIdx.x;
  const int lane = tid & 63;
  const int lr = lane & 15, hi = lane >> 4;
  const int w = tid >> 6;  // wave -> N-group (32 cols)
  const int row0 = blockIdx.y << 6, col0 = blockIdx.x << 7;
  const int NT = K >> 5;
  const int wbase = (tid & ~63) << 4;  // wave-uniform 1KB slots
  const int schunk = tid & 3;
  const int xo = ((hi + (lr >> 1)) & 3) << 4;

  f32x4 acc[4][2];
#pragma unroll
  for (int i = 0; i < 4; ++i)
#pragma unroll
    for (int j = 0; j < 2; ++j) acc[i][j] = f32x4{0.f, 0.f, 0.f, 0.f};

  auto stage = [&](int buf, int kt) {
    const int r = tid >> 2;
    {  // A: 1 shot (4KB, rows 0..63)
      const int ko = ((schunk - (r >> 1)) & 3) << 3;
      gld16(A + (size_t)(row0 + r) * K + (kt << 5) + ko,
            (char*)&lds[buf][0] + wbase);
    }
#pragma unroll
    for (int sh = 0; sh < 2; ++sh) {  // B: 2 shots (rows 0..127)
      const int rb = (sh << 6) + r;
      const int ko = ((schunk - (rb >> 1)) & 3) << 3;
      gld16(Bt + (size_t)(col0 + rb) * K + (kt << 5) + ko,
            (char*)&lds[buf][2048] + (sh << 12) + wbase);
    }
  };

  stage(0, 0);
  __syncthreads();
  int cur = 0;
  for (int kt = 0; kt < NT; ++kt) {
    if (kt + 1 < NT) stage(cur ^ 1, kt + 1);
    const char* As = (const char*)&lds[cur][0];
    const char* Bs = (const char*)&lds[cur][2048];
    s16x8 af[4], bf2[2];
#pragma unroll
    for (int i = 0; i < 4; ++i)
      af[i] = *(const s16x8*)(As + (((i << 4) + lr) << 6) + xo);
#pragma unroll
    for (int j = 0; j < 2; ++j)
      bf2[j] = *(const s16x8*)(Bs + (((w << 5) + (j << 4) + lr) << 6) + xo);
#pragma unroll
    for (int i = 0; i < 4; ++i)
#pragma unroll
      for (int j = 0; j < 2; ++j)
        acc[i][j] =
            __builtin_amdgcn_mfma_f32_16x16x32_bf16(af[i], bf2[j], acc[i][j], 0, 0, 0);
    __syncthreads();
    cur ^= 1;
  }

  const int gc = col0 + (w << 5);
#pragma unroll
  for (int j = 0; j < 2; ++j) {
    const int col = gc + (j << 4) + lr;
    const float bv = (EPI != 0) ? bias[col] : 0.f;
#pragma unroll
    for (int i = 0; i < 4; ++i) {
#pragma unroll
      for (int rg = 0; rg < 4; ++rg) {
        const int row = row0 + (i << 4) + (hi << 2) + rg;
        const size_t off = (size_t)row * N + col;
        float val = acc[i][j][rg] + bv;
        if constexpr (EPI == 1) val += Cf[off];
        if constexpr (EPI == 2) val = fmaxf(val, 0.f);
        if constexpr (EPI == 0 || EPI == 2) Cb[off] = f2bf(val);
        else Cf[off] = val;
      }
    }
  }
}

// ---------------------------------------------------------------------------
// LayerNorm over D=1024, f32 in -> bf16 out. Wave-per-row (no LDS/barrier),
// 4 rows per 256-thread block, shfl-only reduction, 8B vector stores.
// ---------------------------------------------------------------------------
__global__ __launch_bounds__(256) void ln_kernel(const float* __restrict__ x,
                                                 const float* __restrict__ gw,
                                                 const float* __restrict__ bw,
                                                 u16* __restrict__ out) {
  const int lane = threadIdx.x & 63;
  const size_t r = ((size_t)blockIdx.x << 2) + (threadIdx.x >> 6);
  const float* xp = x + (r << 10);
  f32x4 v[4];
  float s = 0.f, q = 0.f;
#pragma unroll
  for (int j = 0; j < 4; ++j) {
    v[j] = *(const f32x4*)(xp + (lane << 2) + (j << 8));
#pragma unroll
    for (int e = 0; e < 4; ++e) {
      s += v[j][e];
      q += v[j][e] * v[j][e];
    }
  }
#pragma unroll
  for (int off = 32; off; off >>= 1) {
    s += __shfl_xor(s, off);
    q += __shfl_xor(q, off);
  }
  const float mean = s * (1.f / 1024.f);
  const float var = q * (1.f / 1024.f) - mean * mean;
  const float rstd = rsqrtf(var + 1e-5f);
  u16* op = out + (r << 10);
#pragma unroll
  for (int j = 0; j < 4; ++j) {
    const f32x4 g4 = *(const f32x4*)(gw + (lane << 2) + (j << 8));
    const f32x4 b4 = *(const f32x4*)(bw + (lane << 2) + (j << 8));
    s16x4 o4;
#pragma unroll
    for (int e = 0; e < 4; ++e)
      o4[e] = (short)f2bf((v[j][e] - mean) * rstd * g4[e] + b4[e]);
    *(s16x4*)(op + (lane << 2) + (j << 8)) = o4;
  }
}

// ---------------------------------------------------------------------------
// Embedding: x[r] = tok_emb[idx[r]] + pos_emb[r % T]
// ---------------------------------------------------------------------------
__global__ __launch_bounds__(256) void embed_kernel(const int* __restrict__ idx,
                                                    const float* __restrict__ tok,
                                                    const float* __restrict__ pos,
                                                    float* __restrict__ x) {
  const int r = blockIdx.x, tid = threadIdx.x;
  const int t = r & (T_ - 1);
  const int tk = idx[r];
  f32x4 a = *(const f32x4*)(tok + ((size_t)tk << 10) + (tid << 2));
  f32x4 p = *(const f32x4*)(pos + ((size_t)t << 10) + (tid << 2));
  *(f32x4*)(x + ((size_t)r << 10) + (tid << 2)) = a + p;
}

// ---------------------------------------------------------------------------
// Transpose + f32->bf16 body: src [K][N] f32 -> dst [N][K] bf16. 32x32 tiles.
// ---------------------------------------------------------------------------
#define TCONV_BODY(SRC, DST, KK, NN)                                           \
  {                                                                            \
    __shared__ float tile[32][33];                                             \
    const int tx = threadIdx.x & 31, ty = threadIdx.x >> 5;                    \
    const int n0 = blockIdx.x << 5, k0 = blockIdx.y << 5;                      \
    _Pragma("unroll")                                                          \
    for (int i = 0; i < 32; i += 8)                                            \
      tile[ty + i][tx] = (SRC)[(size_t)(k0 + ty + i) * (NN) + n0 + tx];        \
    __syncthreads();                                                           \
    _Pragma("unroll")                                                          \
    for (int i = 0; i < 32; i += 8)                                            \
      (DST)[(size_t)(n0 + ty + i) * (KK) + k0 + tx] = f2bf(tile[tx][ty + i]);  \
  }

// All layers' Wq/Wk/Wv/Wp in one launch: grid(32, 32, 32); z = l*4 + m.
__global__ __launch_bounds__(256) void tconv_qkvp(
    const float* __restrict__ Wq, const float* __restrict__ Wk,
    const float* __restrict__ Wv, const float* __restrict__ Wp,
    u16* __restrict__ WqkvT, u16* __restrict__ WpT) {
  const int z = blockIdx.z;
  const int l = z >> 2, m = z & 3;
  const float* src;
  u16* dst;
  if (m == 0) { src = Wq + (size_t)l * D_ * D_; dst = WqkvT + (size_t)l * 3072 * D_; }
  else if (m == 1) { src = Wk + (size_t)l * D_ * D_; dst = WqkvT + (size_t)l * 3072 * D_ + D_ * D_; }
  else if (m == 2) { src = Wv + (size_t)l * D_ * D_; dst = WqkvT + (size_t)l * 3072 * D_ + 2 * D_ * D_; }
  else { src = Wp + (size_t)l * D_ * D_; dst = WpT + (size_t)l * D_ * D_; }
  TCONV_BODY(src, dst, D_, D_)
}

// All layers' W1: grid(128, 32, 8)
__global__ __launch_bounds__(256) void tconv_w1(const float* __restrict__ W1,
                                                u16* __restrict__ W1T) {
  const int l = blockIdx.z;
  TCONV_BODY(W1 + (size_t)l * D_ * FF_, W1T + (size_t)l * FF_ * D_, D_, FF_)
}

// All layers' W2: grid(32, 128, 8)
__global__ __launch_bounds__(256) void tconv_w2(const float* __restrict__ W2,
                                                u16* __restrict__ W2T) {
  const int l = blockIdx.z;
  TCONV_BODY(W2 + (size_t)l * FF_ * D_, W2T + (size_t)l * D_ * FF_, FF_, D_)
}

// Wlm: grid(1000, 32)
__global__ __launch_bounds__(256) void tconv_kernel(const float* __restrict__ src,
                                                    u16* __restrict__ dst, int K, int N) {
  TCONV_BODY(src, dst, K, N)
}

// ---------------------------------------------------------------------------
// Flash attention v3 (causal): QBLK=128 (8 waves, 512 thr), KVBLK=64,
// swapped-QK^T, in-register P, dbuf K/V, exp2-domain softmax,
// XCD-aware (b,h) grouping (8 pairs/XCD -> K/V L2-resident).
// __launch_bounds__(512,4): cap VGPR at 128 -> 2 blocks/CU for latency hiding.
// ---------------------------------------------------------------------------
__global__ __launch_bounds__(512, 4) void fattn_kernel(const u16* __restrict__ qkv,
                                                       u16* __restrict__ o) {
  const int flat = (int)blockIdx.x;
  const int xcd = flat & 7, seq = flat >> 3;
  const int pair = (xcd << 3) + (seq >> 3);
  const int qt = seq & 7;
  const int h = pair & 15, b = pair >> 4;
  const int tid = threadIdx.x;
  const int lane = tid & 63;
  const int lr = lane & 15, hi = lane >> 4;
  const int w = tid >> 6;  // 0..7
  __shared__ alignas(16) u16 Kl[2][4096];  // [buf][kv 64][d 64], 128B rows, XOR-swz
  __shared__ alignas(16) u16 Vt[2][4096];  // [buf][d 64][kv 64], 128B rows, XOR-swz

  const size_t bT = (size_t)(b * T_);
  const int q_row = (qt << 7) + (w << 4) + lr;
  const int qtw = (qt << 1) + (w >> 2);  // wave's 64-row tile index (wave-uniform)
  const size_t qbase = (bT + q_row) * 3072 + (h << 6);
  s16x8 aq[2];
  aq[0] = *(const s16x8*)(qkv + qbase + hi * 8);
  aq[1] = *(const s16x8*)(qkv + qbase + 32 + hi * 8);

  f32x4 ofr[4];
#pragma unroll
  for (int j = 0; j < 4; ++j) ofr[j] = f32x4{0.f, 0.f, 0.f, 0.f};
  float mrun = -1e30f, lsum = 0.f;
  const float SCL = 0.125f * 1.44269504f;  // fold log2(e): softmax in exp2 domain

  uint4 vr0;

#define STAGEK(BUF, KT)                                                        \
  {                                                                            \
    const int r_ = tid >> 3;                                                   \
    const int il_ = (((tid & 7) << 4)) ^ ((r_ & 7) << 4);                      \
    gld16(qkv + (bT + ((KT) << 6) + r_) * 3072 + 1024 + (h << 6) + (il_ >> 1), \
          (char*)&Kl[BUF][0] + ((tid & 448) << 4));                            \
  }
#define LOADV(KT)                                                              \
  {                                                                            \
    vr0 = *(const uint4*)(qkv + (bT + ((KT) << 6) + lane) * 3072 + 2048 +      \
                          (h << 6) + (w << 3));                                \
  }
#define WRITEV(BUF)                                                            \
  {                                                                            \
    const u16* p0_ = (const u16*)&vr0;                                         \
    _Pragma("unroll")                                                          \
    for (int j_ = 0; j_ < 8; ++j_)                                             \
      Vt[BUF][(((w << 3) + j_) << 6) + (lane ^ (j_ << 3))] = p0_[j_];          \
  }

  STAGEK(0, 0)
  LOADV(0)
  asm volatile("s_waitcnt vmcnt(0)" ::: "memory");
  WRITEV(0)
  asm volatile("s_waitcnt lgkmcnt(0)" ::: "memory");
  __builtin_amdgcn_sched_barrier(0);
  __builtin_amdgcn_s_barrier();

  const int nkt = (qt << 1) + 2;
  int cur = 0;
  for (int kt = 0; kt < nkt; ++kt) {
    if (kt + 1 < nkt) {
      STAGEK(cur ^ 1, kt + 1)
      LOADV(kt + 1)
    }

    const bool full = (kt > qtw);  // wave-uniform: fully-masked tile
    f32x4 s[4];
    if (!full) {
      // --- S^T = K Q^T : lane holds S[q=lr][kv = 16j + 4hi + rg] ---
#pragma unroll
      for (int j = 0; j < 4; ++j) s[j] = f32x4{0.f, 0.f, 0.f, 0.f};
      __builtin_amdgcn_s_setprio(1);
#pragma unroll
      for (int kk = 0; kk < 2; ++kk)
#pragma unroll
        for (int j = 0; j < 4; ++j) {
          const int rb = (j << 4) + lr;
          const s16x8 bk = *(const s16x8*)((const char*)&Kl[cur][0] + (rb << 7) +
                                           ((((kk << 2) + hi) ^ (rb & 7)) << 4));
          s[j] = __builtin_amdgcn_mfma_f32_16x16x32_bf16(bk, aq[kk], s[j], 0, 0, 0);
        }
      __builtin_amdgcn_s_setprio(0);
      if (kt == qtw) {
        const int qr = q_row & 63;
#pragma unroll
        for (int j = 0; j < 4; ++j)
#pragma unroll
          for (int rg = 0; rg < 4; ++rg) {
            const int kvr = (j << 4) + (hi << 2) + rg;
            s[j][rg] = (kvr > qr) ? -1e30f : s[j][rg] * SCL;
          }
      } else {
#pragma unroll
        for (int j = 0; j < 4; ++j) s[j] = s[j] * SCL;
      }
    } else {
#pragma unroll
      for (int j = 0; j < 4; ++j) s[j] = f32x4{-1e30f, -1e30f, -1e30f, -1e30f};
    }

    // --- online softmax (exp2 domain), q = lr lane-local; reduce across hi ---
    float mx = fmaxf(fmaxf(s[0][0], s[0][1]), fmaxf(s[0][2], s[0][3]));
#pragma unroll
    for (int j = 1; j < 4; ++j)
#pragma unroll
      for (int rg = 0; rg < 4; ++rg) mx = fmaxf(mx, s[j][rg]);
    mx = fmaxf(mx, __shfl_xor(mx, 16));
    mx = fmaxf(mx, __shfl_xor(mx, 32));
    const float mn = fmaxf(mrun, mx);
    const float sc = exp2f(mrun - mn);
    mrun = mn;
    float rs = 0.f;
#pragma unroll
    for (int j = 0; j < 4; ++j)
#pragma unroll
      for (int rg = 0; rg < 4; ++rg) {
        const float e = exp2f(s[j][rg] - mn);
        s[j][rg] = e;
        rs += e;
      }
    rs += __shfl_xor(rs, 16);
    rs += __shfl_xor(rs, 32);
    lsum = lsum * sc + rs;
    float scO[4];
#pragma unroll
    for (int rg = 0; rg < 4; ++rg) scO[rg] = __shfl(sc, (hi << 2) + rg);
#pragma unroll
    for (int j2 = 0; j2 < 4; ++j2)
#pragma unroll
      for (int rg = 0; rg < 4; ++rg) ofr[j2][rg] *= scO[rg];

    if (!full) {
      // --- pack P (A-frag, pi-mapped): slot s <- s[2kk+(s>>2)][s&3] ---
      s16x8 pb[2];
#pragma unroll
      for (int kk = 0; kk < 2; ++kk)
#pragma unroll
        for (int i = 0; i < 4; ++i) {
          pb[kk][i] = (short)f2bf(s[2 * kk][i]);
          pb[kk][4 + i] = (short)f2bf(s[2 * kk + 1][i]);
        }

      // --- O += P V (V^T b64 reads, pi-mapped) ---
      __builtin_amdgcn_s_setprio(1);
#pragma unroll
      for (int kk = 0; kk < 2; ++kk)
#pragma unroll
        for (int j2 = 0; j2 < 4; ++j2) {
          const int drow = (j2 << 4) + lr;
          const int swz = (drow & 7) << 3;
          const int base = drow << 6;
          const s16x4 lo = *(const s16x4*)&Vt[cur][base + (((kk << 5) + (hi << 2)) ^ swz)];
          const s16x4 hv = *(const s16x4*)&Vt[cur][base + (((kk << 5) + 16 + (hi << 2)) ^ swz)];
          const s16x8 vb = __builtin_shufflevector(lo, hv, 0, 1, 2, 3, 4, 5, 6, 7);
          ofr[j2] = __builtin_amdgcn_mfma_f32_16x16x32_bf16(pb[kk], vb, ofr[j2], 0, 0, 0);
        }
      __builtin_amdgcn_s_setprio(0);
    }

    if (kt + 1 < nkt) {
      asm volatile("s_waitcnt vmcnt(0)" ::: "memory");
      WRITEV(cur ^ 1)
    }
    asm volatile("s_waitcnt lgkmcnt(0)" ::: "memory");
    __builtin_amdgcn_sched_barrier(0);
    __builtin_amdgcn_s_barrier();
    cur ^= 1;
  }

  // --- epilogue: lane holds O[q = w*16 + hi*4+rg][d = j2*16+lr] ---
  const float rinv = 1.f / lsum;
  float rO[4];
#pragma unroll
  for (int rg = 0; rg < 4; ++rg) rO[rg] = __shfl(rinv, (hi << 2) + rg);
#pragma unroll
  for (int j2 = 0; j2 < 4; ++j2)
#pragma unroll
    for (int rg = 0; rg < 4; ++rg) {
      const int row = (qt << 7) + (w << 4) + (hi << 2) + rg;
      const int col = (h << 6) + (j2 << 4) + lr;
      o[(bT + row) * 1024 + col] = f2bf(ofr[j2][rg] * rO[rg]);
    }
#undef STAGEK
#undef LOADV
#undef WRITEV
}

// ---------------------------------------------------------------------------
extern "C" void kernel_launch(void* const* d_in, const int* in_sizes, int n_in,
                              void* d_out, int out_size, void* d_ws, size_t ws_size,
                              hipStream_t stream) {
  (void)in_sizes; (void)n_in; (void)out_size; (void)ws_size;
  const int* idx = (const int*)d_in[0];
  const float* tokE = (const float*)d_in[1];
  const float* posE = (const float*)d_in[2];
  const float* Wq = (const float*)d_in[3];
  const float* Wk = (const float*)d_in[4];
  const float* Wv = (const float*)d_in[5];
  const float* Wp = (const float*)d_in[6];
  const float* bp = (const float*)d_in[7];
  const float* ln1g = (const float*)d_in[8];
  const float* ln1b = (const float*)d_in[9];
  const float* ln2g = (const float*)d_in[10];
  const float* ln2b = (const float*)d_in[11];
  const float* W1 = (const float*)d_in[12];
  const float* b1 = (const float*)d_in[13];
  const float* W2 = (const float*)d_in[14];
  const float* b2 = (const float*)d_in[15];
  const float* lnfg = (const float*)d_in[16];
  const float* lnfb = (const float*)d_in[17];
  const float* Wlm = (const float*)d_in[18];
  const float* blm = (const float*)d_in[19];

  char* p = (char*)d_ws;
  float* x = (float*)p;   p += (size_t)BT_ * D_ * 4;
  u16* xn = (u16*)p;      p += (size_t)BT_ * D_ * 2;
  u16* qkv = (u16*)p;     p += (size_t)BT_ * 3072 * 2;
  u16* ob = (u16*)p;      p += (size_t)BT_ * D_ * 2;
  u16* hb = (u16*)p;      p += (size_t)BT_ * FF_ * 2;
  u16* WqkvT = (u16*)p;   p += (size_t)L_ * 3072 * D_ * 2;
  u16* WpT = (u16*)p;     p += (size_t)L_ * D_ * D_ * 2;
  u16* W1T = (u16*)p;     p += (size_t)L_ * FF_ * D_ * 2;
  u16* W2T = (u16*)p;     p += (size_t)L_ * D_ * FF_ * 2;
  u16* WlmT = (u16*)p;    p += (size_t)V_ * D_ * 2;

  dim3 blk(256);
  dim3 blk512(512);
  // weight convert+transpose (bf16, [N][K]) — fused, 4 launches total
  tconv_qkvp<<<dim3(32, 32, 32), blk, 0, stream>>>(Wq, Wk, Wv, Wp, WqkvT, WpT);
  tconv_w1<<<dim3(128, 32, 8), blk, 0, stream>>>(W1, W1T);
  tconv_w2<<<dim3(32, 128, 8), blk, 0, stream>>>(W2, W2T);
  tconv_kernel<<<dim3(1000, 32), blk, 0, stream>>>(Wlm, WlmT, D_, V_);

  embed_kernel<<<dim3(BT_), blk, 0, stream>>>(idx, tokE, posE, x);

  for (int l = 0; l < L_; ++l) {
    ln_kernel<<<dim3(BT_ / 4), blk, 0, stream>>>(x, ln1g + l * D_, ln1b + l * D_, xn);
    gemm_bt<0><<<dim3(24, 32), blk, 0, stream>>>(xn, WqkvT + (size_t)l * 3072 * D_,
                                                 nullptr, nullptr, qkv, BT_, 3072, D_);
    fattn_kernel<<<dim3(512), blk512, 0, stream>>>(qkv, ob);
    gemm_bt64<1><<<dim3(8, 64), blk, 0, stream>>>(ob, WpT + (size_t)l * D_ * D_,
                                                  bp + l * D_, x, nullptr, BT_, D_, D_);
    ln_kernel<<<dim3(BT_ / 4), blk, 0, stream>>>(x, ln2g + l * D_, ln2b + l * D_, xn);
    gemm_bt<2><<<dim3(32, 32), blk, 0, stream>>>(xn, W1T + (size_t)l * FF_ * D_,
                                                 b1 + l * FF_, nullptr, hb, BT_, FF_, D_);
    gemm_bt64<1><<<dim3(8, 64), blk, 0, stream>>>(hb, W2T + (size_t)l * D_ * FF_,
                                                  b2 + l * D_, x, nullptr, BT_, D_, FF_);
  }
  ln_kernel<<<dim3(BT_ / 4), blk, 0, stream>>>(x, lnfg, lnfb, xn);
  gemm_bt<3><<<dim3(250, 32), blk, 0, stream>>>(xn, WlmT, blm, (float*)d_out, nullptr,
                                                BT_, V_, D_);
}

// Round 11
// 2480.934 us; speedup vs baseline: 1.0332x; 1.0332x over previous
//
#include <hip/hip_runtime.h>
#include <cstdint>

typedef __attribute__((ext_vector_type(4))) float f32x4;
typedef __attribute__((ext_vector_type(8))) short s16x8;
typedef __attribute__((ext_vector_type(4))) short s16x4;
typedef unsigned short u16;
typedef unsigned int u32;
typedef __attribute__((address_space(1))) void gas_void;
typedef __attribute__((address_space(3))) void las_void;

#define B_ 4
#define T_ 1024
#define V_ 32000
#define D_ 1024
#define H_ 16
#define HS_ 64
#define FF_ 4096
#define L_ 8
#define BT_ (B_ * T_)

__device__ __forceinline__ float bf2f(u16 h) { return __uint_as_float(((u32)h) << 16); }
__device__ __forceinline__ u16 f2bf(float f) {
  u32 u = __float_as_uint(f);
  u += 0x7fffu + ((u >> 16) & 1u);
  return (u16)(u >> 16);
}

// async global->LDS, 16B per lane; lds dest must be wave-uniform base (+lane*16 by HW)
__device__ __forceinline__ void gld16(const void* g, void* l) {
  __builtin_amdgcn_global_load_lds((gas_void*)(uintptr_t)g,
                                   (las_void*)(u32)(uintptr_t)l, 16, 0, 0);
}

// LDS 64B-row tiles: physical chunk c holds logical k-chunk l = (c - (row>>1))&3.
// Read side: c = (l + (row>>1))&3 -> conflict-free (2-way is free, m136).

// ---------------------------------------------------------------------------
// gemm256: 256x256 tile, BK=64, 8 waves, 8-phase counted-vmcnt schedule.
// LM head only: XCD chunking (nrowb=16) covers all M rows per B-panel per XCD
// -> WlmT read ~once/XCD (FETCH 0.33GB vs 1.14GB for 128^2 grid). The f32
// logits write-stream thrashes L3, so this locality is mandatory (round 10).
// EPI: 3 = f32 + bias.
// ---------------------------------------------------------------------------
template <int EPI>
__global__ __launch_bounds__(512, 2) void gemm256(
    const u16* __restrict__ A, const u16* __restrict__ Bt,
    const float* __restrict__ bias, float* Cf, u16* Cb,
    int M, int N, int K, int nrowb) {
  __shared__ u16 lds[2][2][2][8192];  // [buf][khalf][A/B][256*32] = 128 KiB
  const int tid = threadIdx.x;
  const int lane = tid & 63;
  const int lr = lane & 15, hi = lane >> 4;
  const int wid = tid >> 6;
  const int wm128 = (wid >> 2) << 7;
  const int wn64 = (wid & 3) << 6;
  const int logical = ((int)blockIdx.x & 7) * ((int)gridDim.x >> 3) + ((int)blockIdx.x >> 3);
  const int row0 = (logical % nrowb) << 8;
  const int col0 = (logical / nrowb) << 8;
  const int NT = K >> 6;
  const int srow = tid >> 2;
  const int schunk = tid & 3;
  const int xo = ((hi + (lr >> 1)) & 3) << 4;

  f32x4 acc[32];
#pragma unroll
  for (int i = 0; i < 32; ++i) acc[i] = f32x4{0.f, 0.f, 0.f, 0.f};
  s16x8 bfr[4];

#define VMW(N) asm volatile("s_waitcnt vmcnt(" #N ")" ::: "memory")

#define STG(DB, DK, OP, KT)                                                    \
  {                                                                            \
    const u16* sp_ = (OP) ? Bt : A;                                            \
    const int base_ = (OP) ? col0 : row0;                                      \
    const int c0_ = ((KT) << 6) + ((DK) << 5);                                 \
    _Pragma("unroll")                                                          \
    for (int sh_ = 0; sh_ < 2; ++sh_) {                                        \
      const int rr_ = (sh_ << 7) + srow;                                       \
      const int ko_ = ((schunk - (rr_ >> 1)) & 3) << 3;                        \
      gld16(sp_ + (size_t)(base_ + rr_) * K + c0_ + ko_,                       \
            (char*)&lds[DB][DK][OP][0] + (sh_ << 13) + (wid << 10));           \
    }                                                                          \
  }

#define PHASE(BUF, MH, KS, LOADB, STG_STMT, VM_STMT)                           \
  {                                                                            \
    __builtin_amdgcn_sched_barrier(0);                                         \
    const char* As_ = (const char*)&lds[BUF][KS][0][0];                        \
    const char* Bs_ = (const char*)&lds[BUF][KS][1][0];                        \
    const int ra_ = wm128 + ((MH) << 6) + lr;                                  \
    s16x8 af_[4];                                                              \
    _Pragma("unroll")                                                          \
    for (int q_ = 0; q_ < 4; ++q_)                                             \
      af_[q_] = *(const s16x8*)(As_ + ((ra_ + (q_ << 4)) << 6) + xo);          \
    if (LOADB) {                                                               \
      _Pragma("unroll")                                                        \
      for (int q_ = 0; q_ < 4; ++q_)                                           \
        bfr[q_] = *(const s16x8*)(Bs_ + ((wn64 + lr + (q_ << 4)) << 6) + xo);  \
    }                                                                          \
    STG_STMT;                                                                  \
    __builtin_amdgcn_sched_barrier(0);                                         \
    __builtin_amdgcn_s_barrier();                                              \
    asm volatile("s_waitcnt lgkmcnt(0)" ::: "memory");                         \
    __builtin_amdgcn_sched_barrier(0);                                         \
    __builtin_amdgcn_s_setprio(1);                                             \
    _Pragma("unroll")                                                          \
    for (int mi_ = 0; mi_ < 4; ++mi_) {                                        \
      _Pragma("unroll")                                                        \
      for (int nj_ = 0; nj_ < 4; ++nj_)                                        \
        acc[((MH)*4 + mi_) * 4 + nj_] = __builtin_amdgcn_mfma_f32_16x16x32_bf16( \
            af_[mi_], bfr[nj_], acc[((MH)*4 + mi_) * 4 + nj_], 0, 0, 0);       \
    }                                                                          \
    __builtin_amdgcn_s_setprio(0);                                             \
    __builtin_amdgcn_sched_barrier(0);                                         \
    VM_STMT;                                                                   \
    __builtin_amdgcn_s_barrier();                                              \
  }

  STG(0, 0, 0, 0)
  STG(0, 0, 1, 0)
  STG(0, 1, 0, 0)
  STG(0, 1, 1, 0)
  STG(1, 0, 0, 1)
  STG(1, 0, 1, 1)
  VMW(8);
  __builtin_amdgcn_s_barrier();

  const int NI = NT >> 1;
  for (int it = 0; it < NI - 1; ++it) {
    const int t1 = 2 * it + 1, t2 = 2 * it + 2, t3 = 2 * it + 3;
    PHASE(0, 0, 0, 1, STG(1, 1, 0, t1), )
    PHASE(0, 1, 0, 0, STG(1, 1, 1, t1), VMW(6))
    PHASE(0, 0, 1, 1, STG(0, 0, 0, t2), )
    PHASE(0, 1, 1, 0, STG(0, 0, 1, t2), VMW(6))
    PHASE(1, 0, 0, 1, STG(0, 1, 0, t2), )
    PHASE(1, 1, 0, 0, STG(0, 1, 1, t2), VMW(6))
    PHASE(1, 0, 1, 1, STG(1, 0, 0, t3), )
    PHASE(1, 1, 1, 0, STG(1, 0, 1, t3), VMW(6))
  }
  {
    PHASE(0, 0, 0, 1, STG(1, 1, 0, NT - 1), )
    PHASE(0, 1, 0, 0, STG(1, 1, 1, NT - 1), VMW(8))
    PHASE(0, 0, 1, 1, (void)0, )
    PHASE(0, 1, 1, 0, (void)0, VMW(4))
    PHASE(1, 0, 0, 1, (void)0, )
    PHASE(1, 1, 0, 0, (void)0, VMW(0))
    PHASE(1, 0, 1, 1, (void)0, )
    PHASE(1, 1, 1, 0, (void)0, )
  }
#undef PHASE
#undef STG
#undef VMW

  const int gr0 = row0 + wm128;
  const int gc0 = col0 + wn64;
#pragma unroll
  for (int nj = 0; nj < 4; ++nj) {
    const int col = gc0 + (nj << 4) + lr;
    const float bv = (EPI != 0) ? bias[col] : 0.f;
#pragma unroll
    for (int mi = 0; mi < 8; ++mi) {
#pragma unroll
      for (int rg = 0; rg < 4; ++rg) {
        const int row = gr0 + (mi << 4) + (hi << 2) + rg;
        const size_t off = (size_t)row * N + col;
        float val = acc[mi * 4 + nj][rg] + bv;
        if constexpr (EPI == 2) val = fmaxf(val, 0.f);
        if constexpr (EPI == 0 || EPI == 2) Cb[off] = f2bf(val);
        else Cf[off] = val;
      }
    }
  }
}

// ---------------------------------------------------------------------------
// GEMM 128x128 (m97 structure): QKV / FF1. 32KB LDS -> 3-4 blk/CU.
// EPI: 0 = bf16 out; 1 = f32 + bias + residual; 2 = bf16 + bias + relu.
// ---------------------------------------------------------------------------
template <int EPI>
__global__ __launch_bounds__(256) void gemm_bt(
    const u16* __restrict__ A, const u16* __restrict__ Bt,
    const float* __restrict__ bias, float* Cf, u16* Cb,
    int M, int N, int K) {
  __shared__ u16 lds[2][2][4096];  // [buf][A/B][128*32] = 32 KiB
  const int tid = threadIdx.x;
  const int lane = tid & 63;
  const int lr = lane & 15, hi = lane >> 4;
  const int wid = tid >> 6;
  const int wm = wid >> 1, wn = wid & 1;
  const int row0 = blockIdx.y << 7, col0 = blockIdx.x << 7;
  const int NT = K >> 5;
  const int wbase = (tid & ~63) << 4;
  const int xo = ((hi + (lr >> 1)) & 3) << 4;

  f32x4 acc[4][4];
#pragma unroll
  for (int i = 0; i < 4; ++i)
#pragma unroll
    for (int j = 0; j < 4; ++j) acc[i][j] = f32x4{0.f, 0.f, 0.f, 0.f};

  auto stage = [&](int buf, int kt) {
#pragma unroll
    for (int c = 0; c < 2; ++c) {
      const int o = (c << 12) + (tid << 4);
      const int r = o >> 6;
      const int ko = ((((o >> 4) & 3) - (r >> 1)) & 3) << 3;
      gld16(A + (size_t)(row0 + r) * K + (kt << 5) + ko,
            (char*)&lds[buf][0][0] + (c << 12) + wbase);
      gld16(Bt + (size_t)(col0 + r) * K + (kt << 5) + ko,
            (char*)&lds[buf][1][0] + (c << 12) + wbase);
    }
  };

  stage(0, 0);
  __syncthreads();
  int cur = 0;
  for (int kt = 0; kt < NT; ++kt) {
    if (kt + 1 < NT) stage(cur ^ 1, kt + 1);
    const char* As = (const char*)&lds[cur][0][0];
    const char* Bs = (const char*)&lds[cur][1][0];
    s16x8 af[4], bfr[4];
#pragma unroll
    for (int i = 0; i < 4; ++i) {
      const int ra = (wm << 6) + (i << 4) + lr;
      af[i] = *(const s16x8*)(As + (ra << 6) + xo);
      const int rb = (wn << 6) + (i << 4) + lr;
      bfr[i] = *(const s16x8*)(Bs + (rb << 6) + xo);
    }
#pragma unroll
    for (int i = 0; i < 4; ++i)
#pragma unroll
      for (int j = 0; j < 4; ++j)
        acc[i][j] =
            __builtin_amdgcn_mfma_f32_16x16x32_bf16(af[i], bfr[j], acc[i][j], 0, 0, 0);
    __syncthreads();
    cur ^= 1;
  }

  const int gr = row0 + (wm << 6);
  const int gc = col0 + (wn << 6);
#pragma unroll
  for (int j = 0; j < 4; ++j) {
    const int col = gc + (j << 4) + lr;
    const float bv = (EPI != 0) ? bias[col] : 0.f;
#pragma unroll
    for (int i = 0; i < 4; ++i) {
#pragma unroll
      for (int rg = 0; rg < 4; ++rg) {
        const int row = gr + (i << 4) + (hi << 2) + rg;
        const size_t off = (size_t)row * N + col;
        float val = acc[i][j][rg] + bv;
        if constexpr (EPI == 1) val += Cf[off];
        if constexpr (EPI == 2) val = fmaxf(val, 0.f);
        if constexpr (EPI == 0 || EPI == 2) Cb[off] = f2bf(val);
        else Cf[off] = val;
      }
    }
  }
}

// ---------------------------------------------------------------------------
// gemm_bt64: 64x128 tile, BK=32, 4 waves. 24KB LDS -> 2+ blocks/CU.
// Used for proj / FF2 (small N): grid (N/128, M/64) = 512 blocks.
// EPI: 1 = f32 out + bias + residual(in-place Cf).
// ---------------------------------------------------------------------------
template <int EPI>
__global__ __launch_bounds__(256) void gemm_bt64(
    const u16* __restrict__ A, const u16* __restrict__ Bt,
    const float* __restrict__ bias, float* Cf, u16* Cb,
    int M, int N, int K) {
  __shared__ u16 lds[2][6144];  // [buf][A 2048 u16 | B 4096 u16] = 24 KiB
  const int tid = threadIdx.x;
  const int lane = tid & 63;
  const int lr = lane & 15, hi = lane >> 4;
  const int w = tid >> 6;
  const int row0 = blockIdx.y << 6, col0 = blockIdx.x << 7;
  const int NT = K >> 5;
  const int wbase = (tid & ~63) << 4;
  const int schunk = tid & 3;
  const int xo = ((hi + (lr >> 1)) & 3) << 4;

  f32x4 acc[4][2];
#pragma unroll
  for (int i = 0; i < 4; ++i)
#pragma unroll
    for (int j = 0; j < 2; ++j) acc[i][j] = f32x4{0.f, 0.f, 0.f, 0.f};

  auto stage = [&](int buf, int kt) {
    const int r = tid >> 2;
    {
      const int ko = ((schunk - (r >> 1)) & 3) << 3;
      gld16(A + (size_t)(row0 + r) * K + (kt << 5) + ko,
            (char*)&lds[buf][0] + wbase);
    }
#pragma unroll
    for (int sh = 0; sh < 2; ++sh) {
      const int rb = (sh << 6) + r;
      const int ko = ((schunk - (rb >> 1)) & 3) << 3;
      gld16(Bt + (size_t)(col0 + rb) * K + (kt << 5) + ko,
            (char*)&lds[buf][2048] + (sh << 12) + wbase);
    }
  };

  stage(0, 0);
  __syncthreads();
  int cur = 0;
  for (int kt = 0; kt < NT; ++kt) {
    if (kt + 1 < NT) stage(cur ^ 1, kt + 1);
    const char* As = (const char*)&lds[cur][0];
    const char* Bs = (const char*)&lds[cur][2048];
    s16x8 af[4], bf2[2];
#pragma unroll
    for (int i = 0; i < 4; ++i)
      af[i] = *(const s16x8*)(As + (((i << 4) + lr) << 6) + xo);
#pragma unroll
    for (int j = 0; j < 2; ++j)
      bf2[j] = *(const s16x8*)(Bs + (((w << 5) + (j << 4) + lr) << 6) + xo);
#pragma unroll
    for (int i = 0; i < 4; ++i)
#pragma unroll
      for (int j = 0; j < 2; ++j)
        acc[i][j] =
            __builtin_amdgcn_mfma_f32_16x16x32_bf16(af[i], bf2[j], acc[i][j], 0, 0, 0);
    __syncthreads();
    cur ^= 1;
  }

  const int gc = col0 + (w << 5);
#pragma unroll
  for (int j = 0; j < 2; ++j) {
    const int col = gc + (j << 4) + lr;
    const float bv = (EPI != 0) ? bias[col] : 0.f;
#pragma unroll
    for (int i = 0; i < 4; ++i) {
#pragma unroll
      for (int rg = 0; rg < 4; ++rg) {
        const int row = row0 + (i << 4) + (hi << 2) + rg;
        const size_t off = (size_t)row * N + col;
        float val = acc[i][j][rg] + bv;
        if constexpr (EPI == 1) val += Cf[off];
        if constexpr (EPI == 2) val = fmaxf(val, 0.f);
        if constexpr (EPI == 0 || EPI == 2) Cb[off] = f2bf(val);
        else Cf[off] = val;
      }
    }
  }
}

// ---------------------------------------------------------------------------
// LayerNorm over D=1024, f32 in -> bf16 out. Wave-per-row, shfl-only.
// ---------------------------------------------------------------------------
__global__ __launch_bounds__(256) void ln_kernel(const float* __restrict__ x,
                                                 const float* __restrict__ gw,
                                                 const float* __restrict__ bw,
                                                 u16* __restrict__ out) {
  const int lane = threadIdx.x & 63;
  const size_t r = ((size_t)blockIdx.x << 2) + (threadIdx.x >> 6);
  const float* xp = x + (r << 10);
  f32x4 v[4];
  float s = 0.f, q = 0.f;
#pragma unroll
  for (int j = 0; j < 4; ++j) {
    v[j] = *(const f32x4*)(xp + (lane << 2) + (j << 8));
#pragma unroll
    for (int e = 0; e < 4; ++e) {
      s += v[j][e];
      q += v[j][e] * v[j][e];
    }
  }
#pragma unroll
  for (int off = 32; off; off >>= 1) {
    s += __shfl_xor(s, off);
    q += __shfl_xor(q, off);
  }
  const float mean = s * (1.f / 1024.f);
  const float var = q * (1.f / 1024.f) - mean * mean;
  const float rstd = rsqrtf(var + 1e-5f);
  u16* op = out + (r << 10);
#pragma unroll
  for (int j = 0; j < 4; ++j) {
    const f32x4 g4 = *(const f32x4*)(gw + (lane << 2) + (j << 8));
    const f32x4 b4 = *(const f32x4*)(bw + (lane << 2) + (j << 8));
    s16x4 o4;
#pragma unroll
    for (int e = 0; e < 4; ++e)
      o4[e] = (short)f2bf((v[j][e] - mean) * rstd * g4[e] + b4[e]);
    *(s16x4*)(op + (lane << 2) + (j << 8)) = o4;
  }
}

// ---------------------------------------------------------------------------
// Embedding: x[r] = tok_emb[idx[r]] + pos_emb[r % T]
// ---------------------------------------------------------------------------
__global__ __launch_bounds__(256) void embed_kernel(const int* __restrict__ idx,
                                                    const float* __restrict__ tok,
                                                    const float* __restrict__ pos,
                                                    float* __restrict__ x) {
  const int r = blockIdx.x, tid = threadIdx.x;
  const int t = r & (T_ - 1);
  const int tk = idx[r];
  f32x4 a = *(const f32x4*)(tok + ((size_t)tk << 10) + (tid << 2));
  f32x4 p = *(const f32x4*)(pos + ((size_t)t << 10) + (tid << 2));
  *(f32x4*)(x + ((size_t)r << 10) + (tid << 2)) = a + p;
}

// ---------------------------------------------------------------------------
// Transpose + f32->bf16, 64x64 tiles: src [K][N] f32 -> dst [N][K] bf16.
// Loads f32x4 (16B/lane), stores s16x8 (16B/lane, 128B contiguous per row).
// LDS [64][65]: load banks (65k+4c+e): 2-way; store banks (8kg+j+n)%32: 2-way.
// ---------------------------------------------------------------------------
#define TCONV_BODY(SRC, DST, KK, NN)                                           \
  {                                                                            \
    __shared__ float tile[64][65];                                             \
    const int tid = threadIdx.x;                                               \
    const int n0 = blockIdx.x << 6, k0 = blockIdx.y << 6;                      \
    _Pragma("unroll")                                                          \
    for (int it = 0; it < 4; ++it) {                                           \
      const int k = (tid >> 4) + (it << 4);                                    \
      const int n = (tid & 15) << 2;                                           \
      *(f32x4*)&tile[k][n] =                                                   \
          *(const f32x4*)((SRC) + (size_t)(k0 + k) * (NN) + n0 + n);           \
    }                                                                          \
    __syncthreads();                                                           \
    _Pragma("unroll")                                                          \
    for (int it = 0; it < 2; ++it) {                                           \
      const int n = (tid >> 3) + (it << 5);                                    \
      const int kp = (tid & 7) << 3;                                           \
      s16x8 o;                                                                 \
      _Pragma("unroll")                                                        \
      for (int j = 0; j < 8; ++j) o[j] = (short)f2bf(tile[kp + j][n]);         \
      *(s16x8*)((DST) + (size_t)(n0 + n) * (KK) + k0 + kp) = o;                \
    }                                                                          \
  }

// All layers' Wq/Wk/Wv/Wp: grid(16, 16, 32); z = l*4 + m.
__global__ __launch_bounds__(256) void tconv_qkvp(
    const float* __restrict__ Wq, const float* __restrict__ Wk,
    const float* __restrict__ Wv, const float* __restrict__ Wp,
    u16* __restrict__ WqkvT, u16* __restrict__ WpT) {
  const int z = blockIdx.z;
  const int l = z >> 2, m = z & 3;
  const float* src;
  u16* dst;
  if (m == 0) { src = Wq + (size_t)l * D_ * D_; dst = WqkvT + (size_t)l * 3072 * D_; }
  else if (m == 1) { src = Wk + (size_t)l * D_ * D_; dst = WqkvT + (size_t)l * 3072 * D_ + D_ * D_; }
  else if (m == 2) { src = Wv + (size_t)l * D_ * D_; dst = WqkvT + (size_t)l * 3072 * D_ + 2 * D_ * D_; }
  else { src = Wp + (size_t)l * D_ * D_; dst = WpT + (size_t)l * D_ * D_; }
  TCONV_BODY(src, dst, D_, D_)
}

// All layers' W1: grid(64, 16, 8)
__global__ __launch_bounds__(256) void tconv_w1(const float* __restrict__ W1,
                                                u16* __restrict__ W1T) {
  const int l = blockIdx.z;
  TCONV_BODY(W1 + (size_t)l * D_ * FF_, W1T + (size_t)l * FF_ * D_, D_, FF_)
}

// All layers' W2: grid(16, 64, 8)
__global__ __launch_bounds__(256) void tconv_w2(const float* __restrict__ W2,
                                                u16* __restrict__ W2T) {
  const int l = blockIdx.z;
  TCONV_BODY(W2 + (size_t)l * FF_ * D_, W2T + (size_t)l * D_ * FF_, FF_, D_)
}

// Wlm: grid(500, 16)
__global__ __launch_bounds__(256) void tconv_kernel(const float* __restrict__ src,
                                                    u16* __restrict__ dst, int K, int N) {
  TCONV_BODY(src, dst, K, N)
}

// ---------------------------------------------------------------------------
// Flash attention v3 (causal): QBLK=128 (8 waves, 512 thr), KVBLK=64,
// swapped-QK^T, in-register P, dbuf K/V, exp2-domain softmax,
// XCD-aware (b,h) grouping (8 pairs/XCD -> K/V L2-resident).
// __launch_bounds__(512,4): cap VGPR at 128 -> 2 blocks/CU.
// ---------------------------------------------------------------------------
__global__ __launch_bounds__(512, 4) void fattn_kernel(const u16* __restrict__ qkv,
                                                       u16* __restrict__ o) {
  const int flat = (int)blockIdx.x;
  const int xcd = flat & 7, seq = flat >> 3;
  const int pair = (xcd << 3) + (seq >> 3);
  const int qt = seq & 7;
  const int h = pair & 15, b = pair >> 4;
  const int tid = threadIdx.x;
  const int lane = tid & 63;
  const int lr = lane & 15, hi = lane >> 4;
  const int w = tid >> 6;
  __shared__ alignas(16) u16 Kl[2][4096];
  __shared__ alignas(16) u16 Vt[2][4096];

  const size_t bT = (size_t)(b * T_);
  const int q_row = (qt << 7) + (w << 4) + lr;
  const int qtw = (qt << 1) + (w >> 2);
  const size_t qbase = (bT + q_row) * 3072 + (h << 6);
  s16x8 aq[2];
  aq[0] = *(const s16x8*)(qkv + qbase + hi * 8);
  aq[1] = *(const s16x8*)(qkv + qbase + 32 + hi * 8);

  f32x4 ofr[4];
#pragma unroll
  for (int j = 0; j < 4; ++j) ofr[j] = f32x4{0.f, 0.f, 0.f, 0.f};
  float mrun = -1e30f, lsum = 0.f;
  const float SCL = 0.125f * 1.44269504f;

  uint4 vr0;

#define STAGEK(BUF, KT)                                                        \
  {                                                                            \
    const int r_ = tid >> 3;                                                   \
    const int il_ = (((tid & 7) << 4)) ^ ((r_ & 7) << 4);                      \
    gld16(qkv + (bT + ((KT) << 6) + r_) * 3072 + 1024 + (h << 6) + (il_ >> 1), \
          (char*)&Kl[BUF][0] + ((tid & 448) << 4));                            \
  }
#define LOADV(KT)                                                              \
  {                                                                            \
    vr0 = *(const uint4*)(qkv + (bT + ((KT) << 6) + lane) * 3072 + 2048 +      \
                          (h << 6) + (w << 3));                                \
  }
#define WRITEV(BUF)                                                            \
  {                                                                            \
    const u16* p0_ = (const u16*)&vr0;                                         \
    _Pragma("unroll")                                                          \
    for (int j_ = 0; j_ < 8; ++j_)                                             \
      Vt[BUF][(((w << 3) + j_) << 6) + (lane ^ (j_ << 3))] = p0_[j_];          \
  }

  STAGEK(0, 0)
  LOADV(0)
  asm volatile("s_waitcnt vmcnt(0)" ::: "memory");
  WRITEV(0)
  asm volatile("s_waitcnt lgkmcnt(0)" ::: "memory");
  __builtin_amdgcn_sched_barrier(0);
  __builtin_amdgcn_s_barrier();

  const int nkt = (qt << 1) + 2;
  int cur = 0;
  for (int kt = 0; kt < nkt; ++kt) {
    if (kt + 1 < nkt) {
      STAGEK(cur ^ 1, kt + 1)
      LOADV(kt + 1)
    }

    const bool full = (kt > qtw);
    f32x4 s[4];
    if (!full) {
#pragma unroll
      for (int j = 0; j < 4; ++j) s[j] = f32x4{0.f, 0.f, 0.f, 0.f};
      __builtin_amdgcn_s_setprio(1);
#pragma unroll
      for (int kk = 0; kk < 2; ++kk)
#pragma unroll
        for (int j = 0; j < 4; ++j) {
          const int rb = (j << 4) + lr;
          const s16x8 bk = *(const s16x8*)((const char*)&Kl[cur][0] + (rb << 7) +
                                           ((((kk << 2) + hi) ^ (rb & 7)) << 4));
          s[j] = __builtin_amdgcn_mfma_f32_16x16x32_bf16(bk, aq[kk], s[j], 0, 0, 0);
        }
      __builtin_amdgcn_s_setprio(0);
      if (kt == qtw) {
        const int qr = q_row & 63;
#pragma unroll
        for (int j = 0; j < 4; ++j)
#pragma unroll
          for (int rg = 0; rg < 4; ++rg) {
            const int kvr = (j << 4) + (hi << 2) + rg;
            s[j][rg] = (kvr > qr) ? -1e30f : s[j][rg] * SCL;
          }
      } else {
#pragma unroll
        for (int j = 0; j < 4; ++j) s[j] = s[j] * SCL;
      }
    } else {
#pragma unroll
      for (int j = 0; j < 4; ++j) s[j] = f32x4{-1e30f, -1e30f, -1e30f, -1e30f};
    }

    float mx = fmaxf(fmaxf(s[0][0], s[0][1]), fmaxf(s[0][2], s[0][3]));
#pragma unroll
    for (int j = 1; j < 4; ++j)
#pragma unroll
      for (int rg = 0; rg < 4; ++rg) mx = fmaxf(mx, s[j][rg]);
    mx = fmaxf(mx, __shfl_xor(mx, 16));
    mx = fmaxf(mx, __shfl_xor(mx, 32));
    const float mn = fmaxf(mrun, mx);
    const float sc = exp2f(mrun - mn);
    mrun = mn;
    float rs = 0.f;
#pragma unroll
    for (int j = 0; j < 4; ++j)
#pragma unroll
      for (int rg = 0; rg < 4; ++rg) {
        const float e = exp2f(s[j][rg] - mn);
        s[j][rg] = e;
        rs += e;
      }
    rs += __shfl_xor(rs, 16);
    rs += __shfl_xor(rs, 32);
    lsum = lsum * sc + rs;
    float scO[4];
#pragma unroll
    for (int rg = 0; rg < 4; ++rg) scO[rg] = __shfl(sc, (hi << 2) + rg);
#pragma unroll
    for (int j2 = 0; j2 < 4; ++j2)
#pragma unroll
      for (int rg = 0; rg < 4; ++rg) ofr[j2][rg] *= scO[rg];

    if (!full) {
      s16x8 pb[2];
#pragma unroll
      for (int kk = 0; kk < 2; ++kk)
#pragma unroll
        for (int i = 0; i < 4; ++i) {
          pb[kk][i] = (short)f2bf(s[2 * kk][i]);
          pb[kk][4 + i] = (short)f2bf(s[2 * kk + 1][i]);
        }

      __builtin_amdgcn_s_setprio(1);
#pragma unroll
      for (int kk = 0; kk < 2; ++kk)
#pragma unroll
        for (int j2 = 0; j2 < 4; ++j2) {
          const int drow = (j2 << 4) + lr;
          const int swz = (drow & 7) << 3;
          const int base = drow << 6;
          const s16x4 lo = *(const s16x4*)&Vt[cur][base + (((kk << 5) + (hi << 2)) ^ swz)];
          const s16x4 hv = *(const s16x4*)&Vt[cur][base + (((kk << 5) + 16 + (hi << 2)) ^ swz)];
          const s16x8 vb = __builtin_shufflevector(lo, hv, 0, 1, 2, 3, 4, 5, 6, 7);
          ofr[j2] = __builtin_amdgcn_mfma_f32_16x16x32_bf16(pb[kk], vb, ofr[j2], 0, 0, 0);
        }
      __builtin_amdgcn_s_setprio(0);
    }

    if (kt + 1 < nkt) {
      asm volatile("s_waitcnt vmcnt(0)" ::: "memory");
      WRITEV(cur ^ 1)
    }
    asm volatile("s_waitcnt lgkmcnt(0)" ::: "memory");
    __builtin_amdgcn_sched_barrier(0);
    __builtin_amdgcn_s_barrier();
    cur ^= 1;
  }

  const float rinv = 1.f / lsum;
  float rO[4];
#pragma unroll
  for (int rg = 0; rg < 4; ++rg) rO[rg] = __shfl(rinv, (hi << 2) + rg);
#pragma unroll
  for (int j2 = 0; j2 < 4; ++j2)
#pragma unroll
    for (int rg = 0; rg < 4; ++rg) {
      const int row = (qt << 7) + (w << 4) + (hi << 2) + rg;
      const int col = (h << 6) + (j2 << 4) + lr;
      o[(bT + row) * 1024 + col] = f2bf(ofr[j2][rg] * rO[rg]);
    }
#undef STAGEK
#undef LOADV
#undef WRITEV
}

// ---------------------------------------------------------------------------
extern "C" void kernel_launch(void* const* d_in, const int* in_sizes, int n_in,
                              void* d_out, int out_size, void* d_ws, size_t ws_size,
                              hipStream_t stream) {
  (void)in_sizes; (void)n_in; (void)out_size; (void)ws_size;
  const int* idx = (const int*)d_in[0];
  const float* tokE = (const float*)d_in[1];
  const float* posE = (const float*)d_in[2];
  const float* Wq = (const float*)d_in[3];
  const float* Wk = (const float*)d_in[4];
  const float* Wv = (const float*)d_in[5];
  const float* Wp = (const float*)d_in[6];
  const float* bp = (const float*)d_in[7];
  const float* ln1g = (const float*)d_in[8];
  const float* ln1b = (const float*)d_in[9];
  const float* ln2g = (const float*)d_in[10];
  const float* ln2b = (const float*)d_in[11];
  const float* W1 = (const float*)d_in[12];
  const float* b1 = (const float*)d_in[13];
  const float* W2 = (const float*)d_in[14];
  const float* b2 = (const float*)d_in[15];
  const float* lnfg = (const float*)d_in[16];
  const float* lnfb = (const float*)d_in[17];
  const float* Wlm = (const float*)d_in[18];
  const float* blm = (const float*)d_in[19];

  char* p = (char*)d_ws;
  float* x = (float*)p;   p += (size_t)BT_ * D_ * 4;
  u16* xn = (u16*)p;      p += (size_t)BT_ * D_ * 2;
  u16* qkv = (u16*)p;     p += (size_t)BT_ * 3072 * 2;
  u16* ob = (u16*)p;      p += (size_t)BT_ * D_ * 2;
  u16* hb = (u16*)p;      p += (size_t)BT_ * FF_ * 2;
  u16* WqkvT = (u16*)p;   p += (size_t)L_ * 3072 * D_ * 2;
  u16* WpT = (u16*)p;     p += (size_t)L_ * D_ * D_ * 2;
  u16* W1T = (u16*)p;     p += (size_t)L_ * FF_ * D_ * 2;
  u16* W2T = (u16*)p;     p += (size_t)L_ * D_ * FF_ * 2;
  u16* WlmT = (u16*)p;    p += (size_t)V_ * D_ * 2;

  dim3 blk(256);
  dim3 blk512(512);
  // weight convert+transpose (bf16, [N][K]) — 64x64 vectorized, 4 launches
  tconv_qkvp<<<dim3(16, 16, 32), blk, 0, stream>>>(Wq, Wk, Wv, Wp, WqkvT, WpT);
  tconv_w1<<<dim3(64, 16, 8), blk, 0, stream>>>(W1, W1T);
  tconv_w2<<<dim3(16, 64, 8), blk, 0, stream>>>(W2, W2T);
  tconv_kernel<<<dim3(500, 16), blk, 0, stream>>>(Wlm, WlmT, D_, V_);

  embed_kernel<<<dim3(BT_), blk, 0, stream>>>(idx, tokE, posE, x);

  for (int l = 0; l < L_; ++l) {
    ln_kernel<<<dim3(BT_ / 4), blk, 0, stream>>>(x, ln1g + l * D_, ln1b + l * D_, xn);
    gemm_bt<0><<<dim3(24, 32), blk, 0, stream>>>(xn, WqkvT + (size_t)l * 3072 * D_,
                                                 nullptr, nullptr, qkv, BT_, 3072, D_);
    fattn_kernel<<<dim3(512), blk512, 0, stream>>>(qkv, ob);
    gemm_bt64<1><<<dim3(8, 64), blk, 0, stream>>>(ob, WpT + (size_t)l * D_ * D_,
                                                  bp + l * D_, x, nullptr, BT_, D_, D_);
    ln_kernel<<<dim3(BT_ / 4), blk, 0, stream>>>(x, ln2g + l * D_, ln2b + l * D_, xn);
    gemm_bt<2><<<dim3(32, 32), blk, 0, stream>>>(xn, W1T + (size_t)l * FF_ * D_,
                                                 b1 + l * FF_, nullptr, hb, BT_, FF_, D_);
    gemm_bt64<1><<<dim3(8, 64), blk, 0, stream>>>(hb, W2T + (size_t)l * D_ * FF_,
                                                  b2 + l * D_, x, nullptr, BT_, D_, FF_);
  }
  ln_kernel<<<dim3(BT_ / 4), blk, 0, stream>>>(x, lnfg, lnfb, xn);
  gemm256<3><<<dim3(2000), blk512, 0, stream>>>(xn, WlmT, blm, (float*)d_out, nullptr,
                                                BT_, V_, D_, 16);
}